// Round 4
// baseline (529.527 us; speedup 1.0000x reference)
//
#include <hip/hip_runtime.h>
#include <cstdint>
#include <cstddef>

#define N_NODES 50000
#define DIM     256
#define NEDGE   800000
#define TOPK    256
#define HBINS   65536
#define CAND_CAP 2048
#define SLOT    64

typedef unsigned long long u64;
typedef float f32x4 __attribute__((ext_vector_type(4)));
typedef __bf16 b16x8 __attribute__((ext_vector_type(8)));
typedef unsigned short us8 __attribute__((ext_vector_type(8)));

__device__ __forceinline__ u64 okey(double d) {
  u64 b = (u64)__double_as_longlong(d);
  return (b & 0x8000000000000000ULL) ? ~b : (b | 0x8000000000000000ULL);
}

__device__ __forceinline__ unsigned short f2bf(float f) {
  unsigned u = __float_as_uint(f);
  return (unsigned short)((u + 0x7fffu + ((u >> 16) & 1u)) >> 16);
}

__device__ __forceinline__ float bf2f(unsigned short u) {
  return __uint_as_float(((unsigned)u) << 16);
}

// ---------------- p norm ----------------
__global__ void pnorm_kernel(const float* __restrict__ p, double* __restrict__ pn) {
  __shared__ double red[256];
  int t = threadIdx.x;
  double v = (double)p[t];
  red[t] = v * v;
  __syncthreads();
  for (int off = 128; off > 0; off >>= 1) {
    if (t < off) red[t] += red[t + off];
    __syncthreads();
  }
  if (t == 0) *pn = sqrt(red[0]);
}

// ---------------- scores (double) + histogram, grid-stride waves ----------------
__global__ __launch_bounds__(256) void score_kernel(const float* __restrict__ X,
                             const float* __restrict__ p,
                             double* __restrict__ scores, unsigned* __restrict__ hist) {
  int lane = threadIdx.x & 63;
  int gw = blockIdx.x * 4 + (threadIdx.x >> 6);
  int nw = gridDim.x * 4;
  float4 p4 = reinterpret_cast<const float4*>(p)[lane];
  for (int row = gw; row < N_NODES; row += nw) {
    float4 x4 = reinterpret_cast<const float4*>(X + (size_t)row * DIM)[lane];
    double s = (double)x4.x * p4.x + (double)x4.y * p4.y +
               (double)x4.z * p4.z + (double)x4.w * p4.w;
    for (int off = 32; off > 0; off >>= 1) s += __shfl_xor(s, off, 64);
    if (lane == 0) {
      scores[row] = s;
      unsigned bin = (unsigned)(okey(s) >> 48);
      atomicAdd(&hist[bin], 1u);
    }
  }
}

// ---------------- find threshold bin ----------------
__global__ __launch_bounds__(1024) void findbin_kernel(const unsigned* __restrict__ hist,
                                                       int* __restrict__ ctrl) {
  __shared__ int sums[1024];
  int t = threadIdx.x;
  int base = t * 64;
  const uint4* h4 = reinterpret_cast<const uint4*>(hist + base);
  int s = 0;
#pragma unroll
  for (int i = 0; i < 16; ++i) {
    uint4 v = h4[i];
    s += (int)(v.x + v.y + v.z + v.w);
  }
  sums[t] = s;
  __syncthreads();
  for (int off = 1; off < 1024; off <<= 1) {
    int x = (t + off < 1024) ? sums[t + off] : 0;
    __syncthreads();
    sums[t] += x;
    __syncthreads();
  }
  int S_incl = sums[t];        // sum of chunks t..1023 (higher bins)
  int S_excl = S_incl - s;     // strictly higher chunks
  if (S_excl < TOPK && S_incl >= TOPK) {
    int c = S_excl;
    int thr = base;
    for (int b = base + 63; b >= base; --b) {
      c += (int)hist[b];
      if (c >= TOPK) { thr = b; break; }
    }
    ctrl[0] = thr;
  }
}

// ---------------- collect candidates ----------------
__global__ void collect_kernel(const double* __restrict__ scores, int* __restrict__ ctrl,
                               double* __restrict__ cand_s, int* __restrict__ cand_i) {
  int i = blockIdx.x * 256 + threadIdx.x;
  if (i >= N_NODES) return;
  double sc = scores[i];
  int bin = (int)(okey(sc) >> 48);
  if (bin >= ctrl[0]) {
    int pos = atomicAdd(&ctrl[1], 1);
    if (pos < CAND_CAP) { cand_s[pos] = sc; cand_i[pos] = i; }
  }
}

// ---------------- bitonic sort candidates, emit top-k idx + gate ----------------
__global__ __launch_bounds__(1024) void sort_kernel(const int* __restrict__ ctrl,
                                                    const double* __restrict__ cand_s,
                                                    const int* __restrict__ cand_i,
                                                    const double* __restrict__ pn,
                                                    int* __restrict__ top_idx,
                                                    float* __restrict__ gate) {
  __shared__ double cs[CAND_CAP];
  __shared__ int ci[CAND_CAP];
  int t = threadIdx.x;
  int cnt = ctrl[1];
  if (cnt > CAND_CAP) cnt = CAND_CAP;
  for (int s = 0; s < CAND_CAP / 1024; ++s) {
    int i = t + s * 1024;
    if (i < cnt) { cs[i] = cand_s[i]; ci[i] = cand_i[i]; }
    else         { cs[i] = -1e308;    ci[i] = 0x7fffffff; }
  }
  __syncthreads();
  for (int k2 = 2; k2 <= CAND_CAP; k2 <<= 1) {
    for (int j = k2 >> 1; j > 0; j >>= 1) {
      for (int s = 0; s < CAND_CAP / 1024; ++s) {
        int i = t + s * 1024;
        int ixj = i ^ j;
        if (ixj > i) {
          double si = cs[i], sx = cs[ixj];
          int ii = ci[i], ix = ci[ixj];
          bool up = ((i & k2) == 0);
          bool sw = up ? ((sx > si) || (sx == si && ix < ii))
                       : ((si > sx) || (si == sx && ii < ix));
          if (sw) { cs[i] = sx; cs[ixj] = si; ci[i] = ix; ci[ixj] = ii; }
        }
      }
      __syncthreads();
    }
  }
  if (t < TOPK) {
    top_idx[t] = ci[t];
    gate[t] = (float)tanh(cs[t] / *pn);
  }
}

// ---------------- x_tilde = X[idx] * gate ----------------
__global__ void xtilde_kernel(const float* __restrict__ X, const int* __restrict__ top_idx,
                              const float* __restrict__ gate, float* __restrict__ xt) {
  int r = blockIdx.x;
  int lane = threadIdx.x;  // 64 threads
  float g = gate[r];
  int src = top_idx[r];
  float4 v = reinterpret_cast<const float4*>(X + (size_t)src * DIM)[lane];
  v.x *= g; v.y *= g; v.z *= g; v.w *= g;
  reinterpret_cast<float4*>(xt + (size_t)r * DIM)[lane] = v;
}

// ---------------- GRU input/hidden GEMMs: 8 rows per block, LDS-staged ----------------
__global__ __launch_bounds__(256) void gru_gemm_kernel(const float* __restrict__ xt,
                                const float* __restrict__ W0,
                                const float* __restrict__ W_ih, const float* __restrict__ W_hh,
                                const float* __restrict__ b_ih, const float* __restrict__ b_hh,
                                float* __restrict__ gi, float* __restrict__ gh) {
  __shared__ float As[8][DIM];
  int tid = threadIdx.x;
  int c = blockIdx.x * 256 + tid;   // 0..767
  int r0 = blockIdx.y * 8;
  int which = blockIdx.z;
  const float* A = which ? W0 : xt;
  const float* W = which ? W_hh : W_ih;
  const float* b = which ? b_hh : b_ih;
  float* outp = which ? gh : gi;
  {
    const float4* src = reinterpret_cast<const float4*>(A + (size_t)r0 * DIM);
    float4* dst = reinterpret_cast<float4*>(&As[0][0]);
    dst[tid] = src[tid];
    dst[tid + 256] = src[tid + 256];
  }
  __syncthreads();
  const float4* Wr = reinterpret_cast<const float4*>(W + (size_t)c * DIM);
  float acc[8] = {0, 0, 0, 0, 0, 0, 0, 0};
#pragma unroll 4
  for (int k4 = 0; k4 < DIM / 4; ++k4) {
    float4 w = Wr[k4];
#pragma unroll
    for (int r = 0; r < 8; ++r) {
      acc[r] += As[r][k4 * 4 + 0] * w.x + As[r][k4 * 4 + 1] * w.y +
                As[r][k4 * 4 + 2] * w.z + As[r][k4 * 4 + 3] * w.w;
    }
  }
  float bc = b[c];
#pragma unroll
  for (int r = 0; r < 8; ++r)
    outp[(size_t)(r0 + r) * 768 + c] = acc[r] + bc;
}

// ---------------- GRU gate fusion -> W_new (bf16, transposed) ----------------
__global__ void wnew_kernel(const float* __restrict__ gi, const float* __restrict__ gh,
                            const float* __restrict__ W0, unsigned short* __restrict__ Wnbt) {
  int rr = blockIdx.x, c = threadIdx.x;   // rr = k index, c = n index
  const float* gir = gi + (size_t)rr * 768;
  const float* ghr = gh + (size_t)rr * 768;
  float i_r = gir[c],       h_r = ghr[c];
  float i_z = gir[c + 256], h_z = ghr[c + 256];
  float i_n = gir[c + 512], h_n = ghr[c + 512];
  float r = 1.f / (1.f + expf(-(i_r + h_r)));
  float z = 1.f / (1.f + expf(-(i_z + h_z)));
  float nn = tanhf(i_n + r * h_n);
  float h = W0[(size_t)rr * DIM + c];
  float w = (1.f - z) * nn + z * h;
  Wnbt[(size_t)c * DIM + rr] = f2bf(w);   // transposed: Wnbt[n][k]
}

// ---------------- xw = X @ W_new via bf16 MFMA, output bf16 ----------------
// block = 256 threads = 4 waves; each wave: 16 rows x 256 cols, K=256
__global__ __launch_bounds__(256) void xw_mfma_kernel(const float* __restrict__ X,
                                                      const unsigned short* __restrict__ Wnbt,
                                                      unsigned short* __restrict__ xwb) {
  int wid = threadIdx.x >> 6, lane = threadIdx.x & 63;
  int r0 = blockIdx.x * 64 + wid * 16;
  if (r0 >= N_NODES) return;
  int rowA = r0 + (lane & 15);
  int kgrp = lane >> 4;              // 0..3
  int koff = kgrp * 8;               // A/B frag: 8 contiguous k per lane

  // load + convert all 8 A fragments (K=256 = 8 x 32)
  const float4* Ar = reinterpret_cast<const float4*>(X + (size_t)rowA * DIM);
  b16x8 afr[8];
#pragma unroll
  for (int kt = 0; kt < 8; ++kt) {
    float4 f0 = Ar[kt * 8 + kgrp * 2 + 0];
    float4 f1 = Ar[kt * 8 + kgrp * 2 + 1];
    union { us8 u; b16x8 b; } cv;
    cv.u[0] = f2bf(f0.x); cv.u[1] = f2bf(f0.y); cv.u[2] = f2bf(f0.z); cv.u[3] = f2bf(f0.w);
    cv.u[4] = f2bf(f1.x); cv.u[5] = f2bf(f1.y); cv.u[6] = f2bf(f1.z); cv.u[7] = f2bf(f1.w);
    afr[kt] = cv.b;
  }

  int colB = lane & 15;
  const unsigned short* Bbase = Wnbt + (size_t)colB * DIM + koff;
  int rr = r0 + kgrp * 4;
#pragma unroll 4
  for (int nf = 0; nf < 16; ++nf) {
    f32x4 acc = {0.f, 0.f, 0.f, 0.f};
    const unsigned short* Bp = Bbase + (size_t)nf * 16 * DIM;
#pragma unroll
    for (int kt = 0; kt < 8; ++kt) {
      b16x8 bfr = *reinterpret_cast<const b16x8*>(Bp + kt * 32);
      acc = __builtin_amdgcn_mfma_f32_16x16x32_bf16(afr[kt], bfr, acc, 0, 0, 0);
    }
    int cc = nf * 16 + colB;
#pragma unroll
    for (int j = 0; j < 4; ++j)
      xwb[(size_t)(rr + j) * DIM + cc] = f2bf(acc[j]);
  }
}

// ---------------- merged: per-dst degree + scatter into fixed-slot buckets ----------------
// stores raw ew in the slot; BOTH dinv factors deferred to agg.
__global__ __launch_bounds__(256) void scatter_kernel(const int* __restrict__ ei,
                               const float* __restrict__ ew,
                               float* __restrict__ deg,
                               int* __restrict__ fill, u64* __restrict__ colval) {
  int stride = gridDim.x * 256;
  for (int e = blockIdx.x * 256 + threadIdx.x; e < NEDGE; e += stride) {
    int s = ei[e], d = ei[NEDGE + e];
    float w = ew[e];
    atomicAdd(&deg[d], w);
    int pos = atomicAdd(&fill[d], 1);
    if (pos < SLOT)
      colval[(size_t)d * SLOT + pos] = ((u64)__float_as_uint(w) << 32) | (unsigned)s;
  }
}

// ---------------- dinv[i] = rsqrt(deg[i]+1) ----------------
__global__ void dinv_kernel(const float* __restrict__ deg, float* __restrict__ dinvb) {
  int i = blockIdx.x * 256 + threadIdx.x;
  if (i >= N_NODES) return;
  dinvb[i] = __frsqrt_rn(deg[i] + 1.0f);
}

// ---------------- aggregation: grid-stride waves, bf16 gather, unroll 4 ----------------
__global__ __launch_bounds__(256) void agg_kernel(const unsigned short* __restrict__ xwb,
                           const float* __restrict__ dinvb,
                           const int* __restrict__ fill, const u64* __restrict__ colval,
                           float* __restrict__ out) {
  int lane = threadIdx.x & 63;
  int gw = blockIdx.x * 4 + (threadIdx.x >> 6);
  int nw = gridDim.x * 4;
  for (int i = gw; i < N_NODES; i += nw) {
    float di = dinvb[i];
    ushort4 sv = reinterpret_cast<const ushort4*>(xwb + (size_t)i * DIM)[lane];
    float4 acc;
    acc.x = di * bf2f(sv.x); acc.y = di * bf2f(sv.y);
    acc.z = di * bf2f(sv.z); acc.w = di * bf2f(sv.w);
    int n = fill[i];
    if (n > SLOT) n = SLOT;
    const u64* cv = colval + (size_t)i * SLOT;
    int j = 0;
    for (; j + 4 <= n; j += 4) {
      u64 a0 = cv[j], a1 = cv[j + 1], a2 = cv[j + 2], a3 = cv[j + 3];
      unsigned c0 = (unsigned)a0, c1 = (unsigned)a1, c2 = (unsigned)a2, c3 = (unsigned)a3;
      ushort4 m0 = reinterpret_cast<const ushort4*>(xwb + (size_t)c0 * DIM)[lane];
      ushort4 m1 = reinterpret_cast<const ushort4*>(xwb + (size_t)c1 * DIM)[lane];
      ushort4 m2 = reinterpret_cast<const ushort4*>(xwb + (size_t)c2 * DIM)[lane];
      ushort4 m3 = reinterpret_cast<const ushort4*>(xwb + (size_t)c3 * DIM)[lane];
      float v0 = __uint_as_float((unsigned)(a0 >> 32)) * dinvb[c0];
      float v1 = __uint_as_float((unsigned)(a1 >> 32)) * dinvb[c1];
      float v2 = __uint_as_float((unsigned)(a2 >> 32)) * dinvb[c2];
      float v3 = __uint_as_float((unsigned)(a3 >> 32)) * dinvb[c3];
      acc.x += v0 * bf2f(m0.x); acc.y += v0 * bf2f(m0.y);
      acc.z += v0 * bf2f(m0.z); acc.w += v0 * bf2f(m0.w);
      acc.x += v1 * bf2f(m1.x); acc.y += v1 * bf2f(m1.y);
      acc.z += v1 * bf2f(m1.z); acc.w += v1 * bf2f(m1.w);
      acc.x += v2 * bf2f(m2.x); acc.y += v2 * bf2f(m2.y);
      acc.z += v2 * bf2f(m2.z); acc.w += v2 * bf2f(m2.w);
      acc.x += v3 * bf2f(m3.x); acc.y += v3 * bf2f(m3.y);
      acc.z += v3 * bf2f(m3.z); acc.w += v3 * bf2f(m3.w);
    }
    for (; j < n; ++j) {
      u64 a0 = cv[j];
      unsigned c0 = (unsigned)a0;
      ushort4 m0 = reinterpret_cast<const ushort4*>(xwb + (size_t)c0 * DIM)[lane];
      float v0 = __uint_as_float((unsigned)(a0 >> 32)) * dinvb[c0];
      acc.x += v0 * bf2f(m0.x); acc.y += v0 * bf2f(m0.y);
      acc.z += v0 * bf2f(m0.z); acc.w += v0 * bf2f(m0.w);
    }
    acc.x *= di; acc.y *= di; acc.z *= di; acc.w *= di;
    reinterpret_cast<float4*>(out + (size_t)i * DIM)[lane] = acc;
  }
}

// ================= host =================
extern "C" void kernel_launch(void* const* d_in, const int* in_sizes, int n_in,
                              void* d_out, int out_size, void* d_ws, size_t ws_size,
                              hipStream_t stream) {
  const float* X    = (const float*)d_in[0];
  const int*   ei   = (const int*)d_in[1];
  const float* ew   = (const float*)d_in[2];
  const float* p    = (const float*)d_in[3];
  const float* W_ih = (const float*)d_in[4];
  const float* W_hh = (const float*)d_in[5];
  const float* b_ih = (const float*)d_in[6];
  const float* b_hh = (const float*)d_in[7];
  const float* W0   = (const float*)d_in[8];
  float* out = (float*)d_out;

  char* ws = (char*)d_ws;
  size_t off = 0;
  auto alloc = [&](size_t bytes) { size_t o = off; off = (off + bytes + 255) & ~(size_t)255; return o; };

  // zero-initialized span first (one memset covers all of it)
  size_t hist_o  = alloc(HBINS * 4);
  size_t ctrl_o  = alloc(64);
  size_t deg_o   = alloc(N_NODES * 4);
  size_t fill_o  = alloc(N_NODES * 4);
  size_t zero_span = off;  // [0, zero_span) gets memset to 0
  size_t scores_o = alloc(N_NODES * 8);
  size_t pn_o     = alloc(8);
  size_t cands_o  = alloc(CAND_CAP * 8);
  size_t candi_o  = alloc(CAND_CAP * 4);
  size_t topidx_o = alloc(TOPK * 4);
  size_t gate_o   = alloc(TOPK * 4);
  size_t dinv_o   = alloc(N_NODES * 4);
  size_t xt_o     = alloc((size_t)TOPK * DIM * 4);
  size_t gi_o     = alloc((size_t)256 * 768 * 4);
  size_t gh_o     = alloc((size_t)256 * 768 * 4);
  size_t wnbt_o   = alloc((size_t)DIM * DIM * 2);     // bf16 transposed W_new
  size_t colval_o = alloc((size_t)N_NODES * SLOT * 8);
  size_t xwb_o    = alloc((size_t)N_NODES * DIM * 2); // bf16 xw
  (void)ws_size; (void)n_in; (void)in_sizes; (void)out_size;

  unsigned* hist  = (unsigned*)(ws + hist_o);
  int*    ctrl    = (int*)(ws + ctrl_o);
  float*  deg     = (float*)(ws + deg_o);
  int*    fill    = (int*)(ws + fill_o);
  double* scores  = (double*)(ws + scores_o);
  double* pn      = (double*)(ws + pn_o);
  double* cand_s  = (double*)(ws + cands_o);
  int*    cand_i  = (int*)(ws + candi_o);
  int*    top_idx = (int*)(ws + topidx_o);
  float*  gate    = (float*)(ws + gate_o);
  float*  dinvb   = (float*)(ws + dinv_o);
  float*  xt      = (float*)(ws + xt_o);
  float*  gi      = (float*)(ws + gi_o);
  float*  gh      = (float*)(ws + gh_o);
  unsigned short* Wnbt = (unsigned short*)(ws + wnbt_o);
  u64*    colval  = (u64*)(ws + colval_o);
  unsigned short* xwb = (unsigned short*)(ws + xwb_o);

  hipMemsetAsync(ws, 0, zero_span, stream);

  pnorm_kernel<<<1, 256, 0, stream>>>(p, pn);
  score_kernel<<<1024, 256, 0, stream>>>(X, p, scores, hist);
  findbin_kernel<<<1, 1024, 0, stream>>>(hist, ctrl);
  collect_kernel<<<(N_NODES + 255) / 256, 256, 0, stream>>>(scores, ctrl, cand_s, cand_i);
  sort_kernel<<<1, 1024, 0, stream>>>(ctrl, cand_s, cand_i, pn, top_idx, gate);
  xtilde_kernel<<<TOPK, 64, 0, stream>>>(X, top_idx, gate, xt);
  gru_gemm_kernel<<<dim3(3, 32, 2), 256, 0, stream>>>(xt, W0, W_ih, W_hh, b_ih, b_hh, gi, gh);
  wnew_kernel<<<256, 256, 0, stream>>>(gi, gh, W0, Wnbt);
  xw_mfma_kernel<<<(N_NODES + 63) / 64, 256, 0, stream>>>(X, Wnbt, xwb);
  scatter_kernel<<<1024, 256, 0, stream>>>(ei, ew, deg, fill, colval);
  dinv_kernel<<<(N_NODES + 255) / 256, 256, 0, stream>>>(deg, dinvb);
  agg_kernel<<<2048, 256, 0, stream>>>(xwb, dinvb, fill, colval, out);
}

// Round 6
// 494.065 us; speedup vs baseline: 1.0718x; 1.0718x over previous
//
#include <hip/hip_runtime.h>
#include <cstdint>
#include <cstddef>

#define N_NODES 50000
#define DIM     256
#define NEDGE   800000
#define TOPK    256
#define HBINS   65536
#define CAND_CAP 2048
#define SLOT    64

typedef unsigned long long u64;
typedef float f32x4 __attribute__((ext_vector_type(4)));
typedef __bf16 b16x8 __attribute__((ext_vector_type(8)));
typedef unsigned short us8 __attribute__((ext_vector_type(8)));

__device__ __forceinline__ u64 okey(double d) {
  u64 b = (u64)__double_as_longlong(d);
  return (b & 0x8000000000000000ULL) ? ~b : (b | 0x8000000000000000ULL);
}

__device__ __forceinline__ unsigned short f2bf(float f) {
  unsigned u = __float_as_uint(f);
  return (unsigned short)((u + 0x7fffu + ((u >> 16) & 1u)) >> 16);
}

__device__ __forceinline__ float bf2f(unsigned short u) {
  return __uint_as_float(((unsigned)u) << 16);
}

// ---------------- scores (double) + histogram, 8-row ILP per wave ----------------
__global__ __launch_bounds__(256) void score_kernel(const float* __restrict__ X,
                             const float* __restrict__ p,
                             double* __restrict__ scores, unsigned* __restrict__ hist) {
  int lane = threadIdx.x & 63;
  int gw = blockIdx.x * 4 + (threadIdx.x >> 6);
  int nw = gridDim.x * 4;
  float4 p4 = reinterpret_cast<const float4*>(p)[lane];
  int row = gw;
  for (; row + 7 * nw < N_NODES; row += 8 * nw) {
    float4 x[8];
#pragma unroll
    for (int u = 0; u < 8; ++u)
      x[u] = reinterpret_cast<const float4*>(X + (size_t)(row + u * nw) * DIM)[lane];
    double s[8];
#pragma unroll
    for (int u = 0; u < 8; ++u)
      s[u] = (double)x[u].x * p4.x + (double)x[u].y * p4.y +
             (double)x[u].z * p4.z + (double)x[u].w * p4.w;
    for (int off = 32; off > 0; off >>= 1) {
#pragma unroll
      for (int u = 0; u < 8; ++u) s[u] += __shfl_xor(s[u], off, 64);
    }
    if (lane == 0) {
#pragma unroll
      for (int u = 0; u < 8; ++u) {
        scores[row + u * nw] = s[u];
        unsigned bin = (unsigned)(okey(s[u]) >> 48);
        atomicAdd(&hist[bin], 1u);
      }
    }
  }
  for (; row < N_NODES; row += nw) {
    float4 x4 = reinterpret_cast<const float4*>(X + (size_t)row * DIM)[lane];
    double s = (double)x4.x * p4.x + (double)x4.y * p4.y +
               (double)x4.z * p4.z + (double)x4.w * p4.w;
    for (int off = 32; off > 0; off >>= 1) s += __shfl_xor(s, off, 64);
    if (lane == 0) {
      scores[row] = s;
      unsigned bin = (unsigned)(okey(s) >> 48);
      atomicAdd(&hist[bin], 1u);
    }
  }
}

// ---------------- find threshold bin ----------------
__global__ __launch_bounds__(1024) void findbin_kernel(const unsigned* __restrict__ hist,
                                                       int* __restrict__ ctrl) {
  __shared__ int sums[1024];
  int t = threadIdx.x;
  int base = t * 64;
  const uint4* h4 = reinterpret_cast<const uint4*>(hist + base);
  int s = 0;
#pragma unroll
  for (int i = 0; i < 16; ++i) {
    uint4 v = h4[i];
    s += (int)(v.x + v.y + v.z + v.w);
  }
  sums[t] = s;
  __syncthreads();
  for (int off = 1; off < 1024; off <<= 1) {
    int x = (t + off < 1024) ? sums[t + off] : 0;
    __syncthreads();
    sums[t] += x;
    __syncthreads();
  }
  int S_incl = sums[t];        // sum of chunks t..1023 (higher bins)
  int S_excl = S_incl - s;     // strictly higher chunks
  if (S_excl < TOPK && S_incl >= TOPK) {
    int c = S_excl;
    int thr = base;
    for (int b = base + 63; b >= base; --b) {
      c += (int)hist[b];
      if (c >= TOPK) { thr = b; break; }
    }
    ctrl[0] = thr;
  }
}

// ---------------- collect candidates ----------------
__global__ void collect_kernel(const double* __restrict__ scores, int* __restrict__ ctrl,
                               double* __restrict__ cand_s, int* __restrict__ cand_i) {
  int i = blockIdx.x * 256 + threadIdx.x;
  if (i >= N_NODES) return;
  double sc = scores[i];
  int bin = (int)(okey(sc) >> 48);
  if (bin >= ctrl[0]) {
    int pos = atomicAdd(&ctrl[1], 1);
    if (pos < CAND_CAP) { cand_s[pos] = sc; cand_i[pos] = i; }
  }
}

// ---------------- bitonic sort candidates (dynamic size) + p-norm + gate ----------------
__global__ __launch_bounds__(1024) void sort_kernel(const int* __restrict__ ctrl,
                                                    const double* __restrict__ cand_s,
                                                    const int* __restrict__ cand_i,
                                                    const float* __restrict__ p,
                                                    int* __restrict__ top_idx,
                                                    float* __restrict__ gate) {
  __shared__ double cs[CAND_CAP];
  __shared__ int ci[CAND_CAP];
  __shared__ double pred[256];
  int t = threadIdx.x;
  if (t < 256) {
    double v = (double)p[t];
    pred[t] = v * v;
  }
  int cnt = ctrl[1];
  if (cnt > CAND_CAP) cnt = CAND_CAP;
  int M = (cnt <= 1024) ? 1024 : CAND_CAP;
  for (int s = 0; s < M / 1024; ++s) {
    int i = t + s * 1024;
    if (i < cnt) { cs[i] = cand_s[i]; ci[i] = cand_i[i]; }
    else         { cs[i] = -1e308;    ci[i] = 0x7fffffff; }
  }
  __syncthreads();
  if (t < 128) pred[t] += pred[t + 128];
  __syncthreads();
  if (t < 64) pred[t] += pred[t + 64];
  __syncthreads();
  if (t < 32) { pred[t] += pred[t + 32]; }
  __syncthreads();
  if (t == 0) {
    double acc = 0.0;
    for (int i = 0; i < 32; ++i) acc += pred[i];
    pred[0] = sqrt(acc);
  }
  for (int k2 = 2; k2 <= M; k2 <<= 1) {
    for (int j = k2 >> 1; j > 0; j >>= 1) {
      for (int s = 0; s < M / 1024; ++s) {
        int i = t + s * 1024;
        int ixj = i ^ j;
        if (ixj > i) {
          double si = cs[i], sx = cs[ixj];
          int ii = ci[i], ix = ci[ixj];
          bool up = ((i & k2) == 0);
          bool sw = up ? ((sx > si) || (sx == si && ix < ii))
                       : ((si > sx) || (si == sx && ii < ix));
          if (sw) { cs[i] = sx; cs[ixj] = si; ci[i] = ix; ci[ixj] = ii; }
        }
      }
      __syncthreads();
    }
  }
  if (t < TOPK) {
    top_idx[t] = ci[t];
    gate[t] = (float)tanh(cs[t] / pred[0]);
  }
}

// ---------------- GRU input/hidden GEMMs: 8 rows per block, LDS-staged ----------------
// which=0 stages gated X[top_idx[r]] rows directly (xtilde fused away)
__global__ __launch_bounds__(256) void gru_gemm_kernel(const float* __restrict__ X,
                                const int* __restrict__ top_idx, const float* __restrict__ gate,
                                const float* __restrict__ W0,
                                const float* __restrict__ W_ih, const float* __restrict__ W_hh,
                                const float* __restrict__ b_ih, const float* __restrict__ b_hh,
                                float* __restrict__ gi, float* __restrict__ gh) {
  __shared__ float As[8][DIM];
  int tid = threadIdx.x;
  int c = blockIdx.x * 256 + tid;   // 0..767
  int r0 = blockIdx.y * 8;
  int which = blockIdx.z;
  const float* W = which ? W_hh : W_ih;
  const float* b = which ? b_hh : b_ih;
  float* outp = which ? gh : gi;
  if (which) {
    const float4* src = reinterpret_cast<const float4*>(W0 + (size_t)r0 * DIM);
    float4* dst = reinterpret_cast<float4*>(&As[0][0]);
    dst[tid] = src[tid];
    dst[tid + 256] = src[tid + 256];
  } else {
#pragma unroll
    for (int h = 0; h < 2; ++h) {
      int idx2 = tid + h * 256;       // 0..511
      int r = idx2 >> 6;              // 0..7
      int e = idx2 & 63;
      int srcrow = top_idx[r0 + r];
      float g = gate[r0 + r];
      float4 v = reinterpret_cast<const float4*>(X + (size_t)srcrow * DIM)[e];
      v.x *= g; v.y *= g; v.z *= g; v.w *= g;
      reinterpret_cast<float4*>(&As[0][0])[idx2] = v;
    }
  }
  __syncthreads();
  const float4* Wr = reinterpret_cast<const float4*>(W + (size_t)c * DIM);
  float acc[8] = {0, 0, 0, 0, 0, 0, 0, 0};
#pragma unroll 4
  for (int k4 = 0; k4 < DIM / 4; ++k4) {
    float4 w = Wr[k4];
#pragma unroll
    for (int r = 0; r < 8; ++r) {
      acc[r] += As[r][k4 * 4 + 0] * w.x + As[r][k4 * 4 + 1] * w.y +
                As[r][k4 * 4 + 2] * w.z + As[r][k4 * 4 + 3] * w.w;
    }
  }
  float bc = b[c];
#pragma unroll
  for (int r = 0; r < 8; ++r)
    outp[(size_t)(r0 + r) * 768 + c] = acc[r] + bc;
}

// ---------------- GRU gate fusion -> W_new (bf16, transposed) ----------------
__global__ void wnew_kernel(const float* __restrict__ gi, const float* __restrict__ gh,
                            const float* __restrict__ W0, unsigned short* __restrict__ Wnbt) {
  int rr = blockIdx.x, c = threadIdx.x;   // rr = k index, c = n index
  const float* gir = gi + (size_t)rr * 768;
  const float* ghr = gh + (size_t)rr * 768;
  float i_r = gir[c],       h_r = ghr[c];
  float i_z = gir[c + 256], h_z = ghr[c + 256];
  float i_n = gir[c + 512], h_n = ghr[c + 512];
  float r = 1.f / (1.f + expf(-(i_r + h_r)));
  float z = 1.f / (1.f + expf(-(i_z + h_z)));
  float nn = tanhf(i_n + r * h_n);
  float h = W0[(size_t)rr * DIM + c];
  float w = (1.f - z) * nn + z * h;
  Wnbt[(size_t)c * DIM + rr] = f2bf(w);   // transposed: Wnbt[n][k]
}

// ---------------- xw = X @ W_new via bf16 MFMA, output bf16 ----------------
__global__ __launch_bounds__(256) void xw_mfma_kernel(const float* __restrict__ X,
                                                      const unsigned short* __restrict__ Wnbt,
                                                      unsigned short* __restrict__ xwb) {
  int wid = threadIdx.x >> 6, lane = threadIdx.x & 63;
  int r0 = blockIdx.x * 64 + wid * 16;
  if (r0 >= N_NODES) return;
  int rowA = r0 + (lane & 15);
  int kgrp = lane >> 4;              // 0..3
  int koff = kgrp * 8;               // A/B frag: 8 contiguous k per lane

  const float4* Ar = reinterpret_cast<const float4*>(X + (size_t)rowA * DIM);
  b16x8 afr[8];
#pragma unroll
  for (int kt = 0; kt < 8; ++kt) {
    float4 f0 = Ar[kt * 8 + kgrp * 2 + 0];
    float4 f1 = Ar[kt * 8 + kgrp * 2 + 1];
    union { us8 u; b16x8 b; } cv;
    cv.u[0] = f2bf(f0.x); cv.u[1] = f2bf(f0.y); cv.u[2] = f2bf(f0.z); cv.u[3] = f2bf(f0.w);
    cv.u[4] = f2bf(f1.x); cv.u[5] = f2bf(f1.y); cv.u[6] = f2bf(f1.z); cv.u[7] = f2bf(f1.w);
    afr[kt] = cv.b;
  }

  int colB = lane & 15;
  const unsigned short* Bbase = Wnbt + (size_t)colB * DIM + koff;
  int rr = r0 + kgrp * 4;
#pragma unroll 4
  for (int nf = 0; nf < 16; ++nf) {
    f32x4 acc = {0.f, 0.f, 0.f, 0.f};
    const unsigned short* Bp = Bbase + (size_t)nf * 16 * DIM;
#pragma unroll
    for (int kt = 0; kt < 8; ++kt) {
      b16x8 bfr = *reinterpret_cast<const b16x8*>(Bp + kt * 32);
      acc = __builtin_amdgcn_mfma_f32_16x16x32_bf16(afr[kt], bfr, acc, 0, 0, 0);
    }
    int cc = nf * 16 + colB;
#pragma unroll
    for (int j = 0; j < 4; ++j)
      xwb[(size_t)(rr + j) * DIM + cc] = f2bf(acc[j]);
  }
}

// ---------------- merged: per-dst degree + scatter into fixed-slot buckets ----------------
__global__ __launch_bounds__(256) void scatter_kernel(const int* __restrict__ ei,
                               const float* __restrict__ ew,
                               float* __restrict__ deg,
                               int* __restrict__ fill, u64* __restrict__ colval) {
  int stride = gridDim.x * 256;
  for (int e = blockIdx.x * 256 + threadIdx.x; e < NEDGE; e += stride) {
    int s = ei[e], d = ei[NEDGE + e];
    float w = ew[e];
    atomicAdd(&deg[d], w);
    int pos = atomicAdd(&fill[d], 1);
    if (pos < SLOT)
      colval[(size_t)d * SLOT + pos] = ((u64)__float_as_uint(w) << 32) | (unsigned)s;
  }
}

// ---------------- aggregation: grid-stride waves, bf16 gather, unroll 8, inline rsqrt ----------------
__global__ __launch_bounds__(256) void agg_kernel(const unsigned short* __restrict__ xwb,
                           const float* __restrict__ deg,
                           const int* __restrict__ fill, const u64* __restrict__ colval,
                           float* __restrict__ out) {
  int lane = threadIdx.x & 63;
  int gw = blockIdx.x * 4 + (threadIdx.x >> 6);
  int nw = gridDim.x * 4;
  for (int i = gw; i < N_NODES; i += nw) {
    float di = __frsqrt_rn(deg[i] + 1.0f);
    ushort4 sv = reinterpret_cast<const ushort4*>(xwb + (size_t)i * DIM)[lane];
    float4 acc;
    acc.x = di * bf2f(sv.x); acc.y = di * bf2f(sv.y);
    acc.z = di * bf2f(sv.z); acc.w = di * bf2f(sv.w);
    int n = fill[i];
    if (n > SLOT) n = SLOT;
    const u64* cv = colval + (size_t)i * SLOT;
    int j = 0;
    for (; j + 8 <= n; j += 8) {
      u64 a[8];
#pragma unroll
      for (int u = 0; u < 8; ++u) a[u] = cv[j + u];
      unsigned c[8];
      ushort4 m[8];
      float dg[8];
#pragma unroll
      for (int u = 0; u < 8; ++u) {
        c[u] = (unsigned)a[u];
        m[u] = reinterpret_cast<const ushort4*>(xwb + (size_t)c[u] * DIM)[lane];
        dg[u] = deg[c[u]];
      }
#pragma unroll
      for (int u = 0; u < 8; ++u) {
        float v = __uint_as_float((unsigned)(a[u] >> 32)) * __frsqrt_rn(dg[u] + 1.0f);
        acc.x += v * bf2f(m[u].x); acc.y += v * bf2f(m[u].y);
        acc.z += v * bf2f(m[u].z); acc.w += v * bf2f(m[u].w);
      }
    }
    for (; j < n; ++j) {
      u64 a0 = cv[j];
      unsigned c0 = (unsigned)a0;
      ushort4 m0 = reinterpret_cast<const ushort4*>(xwb + (size_t)c0 * DIM)[lane];
      float v0 = __uint_as_float((unsigned)(a0 >> 32)) * __frsqrt_rn(deg[c0] + 1.0f);
      acc.x += v0 * bf2f(m0.x); acc.y += v0 * bf2f(m0.y);
      acc.z += v0 * bf2f(m0.z); acc.w += v0 * bf2f(m0.w);
    }
    acc.x *= di; acc.y *= di; acc.z *= di; acc.w *= di;
    reinterpret_cast<float4*>(out + (size_t)i * DIM)[lane] = acc;
  }
}

// ================= host =================
extern "C" void kernel_launch(void* const* d_in, const int* in_sizes, int n_in,
                              void* d_out, int out_size, void* d_ws, size_t ws_size,
                              hipStream_t stream) {
  const float* X    = (const float*)d_in[0];
  const int*   ei   = (const int*)d_in[1];
  const float* ew   = (const float*)d_in[2];
  const float* p    = (const float*)d_in[3];
  const float* W_ih = (const float*)d_in[4];
  const float* W_hh = (const float*)d_in[5];
  const float* b_ih = (const float*)d_in[6];
  const float* b_hh = (const float*)d_in[7];
  const float* W0   = (const float*)d_in[8];
  float* out = (float*)d_out;

  char* ws = (char*)d_ws;
  size_t off = 0;
  auto alloc = [&](size_t bytes) { size_t o = off; off = (off + bytes + 255) & ~(size_t)255; return o; };

  // zero-initialized span first (one memset covers all of it)
  size_t hist_o  = alloc(HBINS * 4);
  size_t ctrl_o  = alloc(64);
  size_t deg_o   = alloc(N_NODES * 4);
  size_t fill_o  = alloc(N_NODES * 4);
  size_t zero_span = off;  // [0, zero_span) gets memset to 0
  size_t scores_o = alloc(N_NODES * 8);
  size_t cands_o  = alloc(CAND_CAP * 8);
  size_t candi_o  = alloc(CAND_CAP * 4);
  size_t topidx_o = alloc(TOPK * 4);
  size_t gate_o   = alloc(TOPK * 4);
  size_t gi_o     = alloc((size_t)256 * 768 * 4);
  size_t gh_o     = alloc((size_t)256 * 768 * 4);
  size_t wnbt_o   = alloc((size_t)DIM * DIM * 2);     // bf16 transposed W_new
  size_t colval_o = alloc((size_t)N_NODES * SLOT * 8);
  size_t xwb_o    = alloc((size_t)N_NODES * DIM * 2); // bf16 xw
  (void)ws_size; (void)n_in; (void)in_sizes; (void)out_size;

  unsigned* hist  = (unsigned*)(ws + hist_o);
  int*    ctrl    = (int*)(ws + ctrl_o);
  float*  deg     = (float*)(ws + deg_o);
  int*    fill    = (int*)(ws + fill_o);
  double* scores  = (double*)(ws + scores_o);
  double* cand_s  = (double*)(ws + cands_o);
  int*    cand_i  = (int*)(ws + candi_o);
  int*    top_idx = (int*)(ws + topidx_o);
  float*  gate    = (float*)(ws + gate_o);
  float*  gi      = (float*)(ws + gi_o);
  float*  gh      = (float*)(ws + gh_o);
  unsigned short* Wnbt = (unsigned short*)(ws + wnbt_o);
  u64*    colval  = (u64*)(ws + colval_o);
  unsigned short* xwb = (unsigned short*)(ws + xwb_o);

  hipMemsetAsync(ws, 0, zero_span, stream);

  score_kernel<<<1563, 256, 0, stream>>>(X, p, scores, hist);
  findbin_kernel<<<1, 1024, 0, stream>>>(hist, ctrl);
  collect_kernel<<<(N_NODES + 255) / 256, 256, 0, stream>>>(scores, ctrl, cand_s, cand_i);
  sort_kernel<<<1, 1024, 0, stream>>>(ctrl, cand_s, cand_i, p, top_idx, gate);
  gru_gemm_kernel<<<dim3(3, 32, 2), 256, 0, stream>>>(X, top_idx, gate, W0, W_ih, W_hh,
                                                      b_ih, b_hh, gi, gh);
  wnew_kernel<<<256, 256, 0, stream>>>(gi, gh, W0, Wnbt);
  xw_mfma_kernel<<<(N_NODES + 63) / 64, 256, 0, stream>>>(X, Wnbt, xwb);
  scatter_kernel<<<1024, 256, 0, stream>>>(ei, ew, deg, fill, colval);
  agg_kernel<<<2048, 256, 0, stream>>>(xwb, deg, fill, colval, out);
}

// Round 7
// 434.141 us; speedup vs baseline: 1.2197x; 1.1380x over previous
//
#include <hip/hip_runtime.h>
#include <cstdint>
#include <cstddef>

#define N_NODES 50000
#define DIM     256
#define NEDGE   800000
#define TOPK    256
#define HBINS   65536
#define CAND_CAP 2048
#define SLOT    64
#define SROWS   32   // rows per block iteration in score (4 waves x 8)

typedef unsigned long long u64;
typedef float f32x4 __attribute__((ext_vector_type(4)));
typedef __bf16 b16x8 __attribute__((ext_vector_type(8)));
typedef unsigned short us8 __attribute__((ext_vector_type(8)));

__device__ __forceinline__ u64 okey(double d) {
  u64 b = (u64)__double_as_longlong(d);
  return (b & 0x8000000000000000ULL) ? ~b : (b | 0x8000000000000000ULL);
}

__device__ __forceinline__ unsigned short f2bf(float f) {
  unsigned u = __float_as_uint(f);
  return (unsigned short)((u + 0x7fffu + ((u >> 16) & 1u)) >> 16);
}

__device__ __forceinline__ float bf2f(unsigned short u) {
  return __uint_as_float(((unsigned)u) << 16);
}

// ---------------- workspace zero-init (also absorbs any queue-wait attribution) ----------------
__global__ __launch_bounds__(256) void init_kernel(unsigned* __restrict__ w, int nwords) {
  int stride = gridDim.x * 256;
  for (int i = blockIdx.x * 256 + threadIdx.x; i < nwords; i += stride) w[i] = 0u;
}

// ---------------- scores (f64) + histogram: 8-row ILP loads, LDS-transpose reduce ----------------
__global__ __launch_bounds__(256) void score_kernel(const float* __restrict__ X,
                             const float* __restrict__ p,
                             double* __restrict__ scores, unsigned* __restrict__ hist) {
  __shared__ double part[SROWS][65];   // [row][lane], pad row stride to 65 doubles
  int tid = threadIdx.x;
  int lane = tid & 63, wid = tid >> 6;
  float4 p4 = reinterpret_cast<const float4*>(p)[lane];
  int nblk_rows = gridDim.x * SROWS;
  for (int rb = blockIdx.x * SROWS; rb < N_NODES; rb += nblk_rows) {
    // phase 1: each wave computes lane-partials for 8 rows (8 independent loads in flight)
    int r0 = rb + wid * 8;
    float4 x[8];
#pragma unroll
    for (int u = 0; u < 8; ++u) {
      int r = r0 + u;
      x[u] = (r < N_NODES)
           ? reinterpret_cast<const float4*>(X + (size_t)r * DIM)[lane]
           : make_float4(0.f, 0.f, 0.f, 0.f);
    }
#pragma unroll
    for (int u = 0; u < 8; ++u) {
      double s = (double)x[u].x * p4.x + (double)x[u].y * p4.y +
                 (double)x[u].z * p4.z + (double)x[u].w * p4.w;
      part[wid * 8 + u][lane] = s;
    }
    __syncthreads();
    // phase 2: threads 0..31 each linearly sum one row's 64 partials (4-way ILP)
    if (tid < SROWS) {
      int row = rb + tid;
      if (row < N_NODES) {
        const double* pr = part[tid];
        double a0 = 0.0, a1 = 0.0, a2 = 0.0, a3 = 0.0;
#pragma unroll
        for (int l = 0; l < 64; l += 4) {
          a0 += pr[l + 0]; a1 += pr[l + 1]; a2 += pr[l + 2]; a3 += pr[l + 3];
        }
        double s = (a0 + a1) + (a2 + a3);
        scores[row] = s;
        unsigned bin = (unsigned)(okey(s) >> 48);
        atomicAdd(&hist[bin], 1u);
      }
    }
    __syncthreads();
  }
}

// ---------------- find threshold bin ----------------
__global__ __launch_bounds__(1024) void findbin_kernel(const unsigned* __restrict__ hist,
                                                       int* __restrict__ ctrl) {
  __shared__ int sums[1024];
  int t = threadIdx.x;
  int base = t * 64;
  const uint4* h4 = reinterpret_cast<const uint4*>(hist + base);
  int s = 0;
#pragma unroll
  for (int i = 0; i < 16; ++i) {
    uint4 v = h4[i];
    s += (int)(v.x + v.y + v.z + v.w);
  }
  sums[t] = s;
  __syncthreads();
  for (int off = 1; off < 1024; off <<= 1) {
    int x = (t + off < 1024) ? sums[t + off] : 0;
    __syncthreads();
    sums[t] += x;
    __syncthreads();
  }
  int S_incl = sums[t];        // sum of chunks t..1023 (higher bins)
  int S_excl = S_incl - s;     // strictly higher chunks
  if (S_excl < TOPK && S_incl >= TOPK) {
    int c = S_excl;
    int thr = base;
    for (int b = base + 63; b >= base; --b) {
      c += (int)hist[b];
      if (c >= TOPK) { thr = b; break; }
    }
    ctrl[0] = thr;
  }
}

// ---------------- collect candidates ----------------
__global__ void collect_kernel(const double* __restrict__ scores, int* __restrict__ ctrl,
                               double* __restrict__ cand_s, int* __restrict__ cand_i) {
  int i = blockIdx.x * 256 + threadIdx.x;
  if (i >= N_NODES) return;
  double sc = scores[i];
  int bin = (int)(okey(sc) >> 48);
  if (bin >= ctrl[0]) {
    int pos = atomicAdd(&ctrl[1], 1);
    if (pos < CAND_CAP) { cand_s[pos] = sc; cand_i[pos] = i; }
  }
}

// ---------------- bitonic sort candidates (dynamic size) + p-norm + gate ----------------
__global__ __launch_bounds__(1024) void sort_kernel(const int* __restrict__ ctrl,
                                                    const double* __restrict__ cand_s,
                                                    const int* __restrict__ cand_i,
                                                    const float* __restrict__ p,
                                                    int* __restrict__ top_idx,
                                                    float* __restrict__ gate) {
  __shared__ double cs[CAND_CAP];
  __shared__ int ci[CAND_CAP];
  __shared__ double pred[256];
  int t = threadIdx.x;
  if (t < 256) {
    double v = (double)p[t];
    pred[t] = v * v;
  }
  int cnt = ctrl[1];
  if (cnt > CAND_CAP) cnt = CAND_CAP;
  int M = (cnt <= 1024) ? 1024 : CAND_CAP;
  for (int s = 0; s < M / 1024; ++s) {
    int i = t + s * 1024;
    if (i < cnt) { cs[i] = cand_s[i]; ci[i] = cand_i[i]; }
    else         { cs[i] = -1e308;    ci[i] = 0x7fffffff; }
  }
  __syncthreads();
  if (t < 128) pred[t] += pred[t + 128];
  __syncthreads();
  if (t < 64) pred[t] += pred[t + 64];
  __syncthreads();
  if (t < 32) { pred[t] += pred[t + 32]; }
  __syncthreads();
  if (t == 0) {
    double acc = 0.0;
    for (int i = 0; i < 32; ++i) acc += pred[i];
    pred[0] = sqrt(acc);
  }
  for (int k2 = 2; k2 <= M; k2 <<= 1) {
    for (int j = k2 >> 1; j > 0; j >>= 1) {
      for (int s = 0; s < M / 1024; ++s) {
        int i = t + s * 1024;
        int ixj = i ^ j;
        if (ixj > i) {
          double si = cs[i], sx = cs[ixj];
          int ii = ci[i], ix = ci[ixj];
          bool up = ((i & k2) == 0);
          bool sw = up ? ((sx > si) || (sx == si && ix < ii))
                       : ((si > sx) || (si == sx && ii < ix));
          if (sw) { cs[i] = sx; cs[ixj] = si; ci[i] = ix; ci[ixj] = ii; }
        }
      }
      __syncthreads();
    }
  }
  if (t < TOPK) {
    top_idx[t] = ci[t];
    gate[t] = (float)tanh(cs[t] / pred[0]);
  }
}

// ---------------- GRU input/hidden GEMMs: 8 rows per block, LDS-staged ----------------
// which=0 stages gated X[top_idx[r]] rows directly (xtilde fused away)
__global__ __launch_bounds__(256) void gru_gemm_kernel(const float* __restrict__ X,
                                const int* __restrict__ top_idx, const float* __restrict__ gate,
                                const float* __restrict__ W0,
                                const float* __restrict__ W_ih, const float* __restrict__ W_hh,
                                const float* __restrict__ b_ih, const float* __restrict__ b_hh,
                                float* __restrict__ gi, float* __restrict__ gh) {
  __shared__ float As[8][DIM];
  int tid = threadIdx.x;
  int c = blockIdx.x * 256 + tid;   // 0..767
  int r0 = blockIdx.y * 8;
  int which = blockIdx.z;
  const float* W = which ? W_hh : W_ih;
  const float* b = which ? b_hh : b_ih;
  float* outp = which ? gh : gi;
  if (which) {
    const float4* src = reinterpret_cast<const float4*>(W0 + (size_t)r0 * DIM);
    float4* dst = reinterpret_cast<float4*>(&As[0][0]);
    dst[tid] = src[tid];
    dst[tid + 256] = src[tid + 256];
  } else {
#pragma unroll
    for (int h = 0; h < 2; ++h) {
      int idx2 = tid + h * 256;       // 0..511
      int r = idx2 >> 6;              // 0..7
      int e = idx2 & 63;
      int srcrow = top_idx[r0 + r];
      float g = gate[r0 + r];
      float4 v = reinterpret_cast<const float4*>(X + (size_t)srcrow * DIM)[e];
      v.x *= g; v.y *= g; v.z *= g; v.w *= g;
      reinterpret_cast<float4*>(&As[0][0])[idx2] = v;
    }
  }
  __syncthreads();
  const float4* Wr = reinterpret_cast<const float4*>(W + (size_t)c * DIM);
  float acc[8] = {0, 0, 0, 0, 0, 0, 0, 0};
#pragma unroll 4
  for (int k4 = 0; k4 < DIM / 4; ++k4) {
    float4 w = Wr[k4];
#pragma unroll
    for (int r = 0; r < 8; ++r) {
      acc[r] += As[r][k4 * 4 + 0] * w.x + As[r][k4 * 4 + 1] * w.y +
                As[r][k4 * 4 + 2] * w.z + As[r][k4 * 4 + 3] * w.w;
    }
  }
  float bc = b[c];
#pragma unroll
  for (int r = 0; r < 8; ++r)
    outp[(size_t)(r0 + r) * 768 + c] = acc[r] + bc;
}

// ---------------- GRU gate fusion -> W_new (bf16, transposed) ----------------
__global__ void wnew_kernel(const float* __restrict__ gi, const float* __restrict__ gh,
                            const float* __restrict__ W0, unsigned short* __restrict__ Wnbt) {
  int rr = blockIdx.x, c = threadIdx.x;   // rr = k index, c = n index
  const float* gir = gi + (size_t)rr * 768;
  const float* ghr = gh + (size_t)rr * 768;
  float i_r = gir[c],       h_r = ghr[c];
  float i_z = gir[c + 256], h_z = ghr[c + 256];
  float i_n = gir[c + 512], h_n = ghr[c + 512];
  float r = 1.f / (1.f + expf(-(i_r + h_r)));
  float z = 1.f / (1.f + expf(-(i_z + h_z)));
  float nn = tanhf(i_n + r * h_n);
  float h = W0[(size_t)rr * DIM + c];
  float w = (1.f - z) * nn + z * h;
  Wnbt[(size_t)c * DIM + rr] = f2bf(w);   // transposed: Wnbt[n][k]
}

// ---------------- xw = X @ W_new via bf16 MFMA, output bf16 ----------------
__global__ __launch_bounds__(256) void xw_mfma_kernel(const float* __restrict__ X,
                                                      const unsigned short* __restrict__ Wnbt,
                                                      unsigned short* __restrict__ xwb) {
  int wid = threadIdx.x >> 6, lane = threadIdx.x & 63;
  int r0 = blockIdx.x * 64 + wid * 16;
  if (r0 >= N_NODES) return;
  int rowA = r0 + (lane & 15);
  int kgrp = lane >> 4;              // 0..3
  int koff = kgrp * 8;               // A/B frag: 8 contiguous k per lane

  const float4* Ar = reinterpret_cast<const float4*>(X + (size_t)rowA * DIM);
  b16x8 afr[8];
#pragma unroll
  for (int kt = 0; kt < 8; ++kt) {
    float4 f0 = Ar[kt * 8 + kgrp * 2 + 0];
    float4 f1 = Ar[kt * 8 + kgrp * 2 + 1];
    union { us8 u; b16x8 b; } cv;
    cv.u[0] = f2bf(f0.x); cv.u[1] = f2bf(f0.y); cv.u[2] = f2bf(f0.z); cv.u[3] = f2bf(f0.w);
    cv.u[4] = f2bf(f1.x); cv.u[5] = f2bf(f1.y); cv.u[6] = f2bf(f1.z); cv.u[7] = f2bf(f1.w);
    afr[kt] = cv.b;
  }

  int colB = lane & 15;
  const unsigned short* Bbase = Wnbt + (size_t)colB * DIM + koff;
  int rr = r0 + kgrp * 4;
#pragma unroll 4
  for (int nf = 0; nf < 16; ++nf) {
    f32x4 acc = {0.f, 0.f, 0.f, 0.f};
    const unsigned short* Bp = Bbase + (size_t)nf * 16 * DIM;
#pragma unroll
    for (int kt = 0; kt < 8; ++kt) {
      b16x8 bfr = *reinterpret_cast<const b16x8*>(Bp + kt * 32);
      acc = __builtin_amdgcn_mfma_f32_16x16x32_bf16(afr[kt], bfr, acc, 0, 0, 0);
    }
    int cc = nf * 16 + colB;
#pragma unroll
    for (int j = 0; j < 4; ++j)
      xwb[(size_t)(rr + j) * DIM + cc] = f2bf(acc[j]);
  }
}

// ---------------- merged: per-dst degree + scatter into fixed-slot buckets ----------------
__global__ __launch_bounds__(256) void scatter_kernel(const int* __restrict__ ei,
                               const float* __restrict__ ew,
                               float* __restrict__ deg,
                               int* __restrict__ fill, u64* __restrict__ colval) {
  int stride = gridDim.x * 256;
  for (int e = blockIdx.x * 256 + threadIdx.x; e < NEDGE; e += stride) {
    int s = ei[e], d = ei[NEDGE + e];
    float w = ew[e];
    atomicAdd(&deg[d], w);
    int pos = atomicAdd(&fill[d], 1);
    if (pos < SLOT)
      colval[(size_t)d * SLOT + pos] = ((u64)__float_as_uint(w) << 32) | (unsigned)s;
  }
}

// ---------------- aggregation: grid-stride waves, bf16 gather, unroll 8, inline rsqrt ----------------
__global__ __launch_bounds__(256) void agg_kernel(const unsigned short* __restrict__ xwb,
                           const float* __restrict__ deg,
                           const int* __restrict__ fill, const u64* __restrict__ colval,
                           float* __restrict__ out) {
  int lane = threadIdx.x & 63;
  int gw = blockIdx.x * 4 + (threadIdx.x >> 6);
  int nw = gridDim.x * 4;
  for (int i = gw; i < N_NODES; i += nw) {
    float di = __frsqrt_rn(deg[i] + 1.0f);
    ushort4 sv = reinterpret_cast<const ushort4*>(xwb + (size_t)i * DIM)[lane];
    float4 acc;
    acc.x = di * bf2f(sv.x); acc.y = di * bf2f(sv.y);
    acc.z = di * bf2f(sv.z); acc.w = di * bf2f(sv.w);
    int n = fill[i];
    if (n > SLOT) n = SLOT;
    const u64* cv = colval + (size_t)i * SLOT;
    int j = 0;
    for (; j + 8 <= n; j += 8) {
      u64 a[8];
#pragma unroll
      for (int u = 0; u < 8; ++u) a[u] = cv[j + u];
      unsigned c[8];
      ushort4 m[8];
      float dg[8];
#pragma unroll
      for (int u = 0; u < 8; ++u) {
        c[u] = (unsigned)a[u];
        m[u] = reinterpret_cast<const ushort4*>(xwb + (size_t)c[u] * DIM)[lane];
        dg[u] = deg[c[u]];
      }
#pragma unroll
      for (int u = 0; u < 8; ++u) {
        float v = __uint_as_float((unsigned)(a[u] >> 32)) * __frsqrt_rn(dg[u] + 1.0f);
        acc.x += v * bf2f(m[u].x); acc.y += v * bf2f(m[u].y);
        acc.z += v * bf2f(m[u].z); acc.w += v * bf2f(m[u].w);
      }
    }
    for (; j < n; ++j) {
      u64 a0 = cv[j];
      unsigned c0 = (unsigned)a0;
      ushort4 m0 = reinterpret_cast<const ushort4*>(xwb + (size_t)c0 * DIM)[lane];
      float v0 = __uint_as_float((unsigned)(a0 >> 32)) * __frsqrt_rn(deg[c0] + 1.0f);
      acc.x += v0 * bf2f(m0.x); acc.y += v0 * bf2f(m0.y);
      acc.z += v0 * bf2f(m0.z); acc.w += v0 * bf2f(m0.w);
    }
    acc.x *= di; acc.y *= di; acc.z *= di; acc.w *= di;
    reinterpret_cast<float4*>(out + (size_t)i * DIM)[lane] = acc;
  }
}

// ================= host =================
extern "C" void kernel_launch(void* const* d_in, const int* in_sizes, int n_in,
                              void* d_out, int out_size, void* d_ws, size_t ws_size,
                              hipStream_t stream) {
  const float* X    = (const float*)d_in[0];
  const int*   ei   = (const int*)d_in[1];
  const float* ew   = (const float*)d_in[2];
  const float* p    = (const float*)d_in[3];
  const float* W_ih = (const float*)d_in[4];
  const float* W_hh = (const float*)d_in[5];
  const float* b_ih = (const float*)d_in[6];
  const float* b_hh = (const float*)d_in[7];
  const float* W0   = (const float*)d_in[8];
  float* out = (float*)d_out;

  char* ws = (char*)d_ws;
  size_t off = 0;
  auto alloc = [&](size_t bytes) { size_t o = off; off = (off + bytes + 255) & ~(size_t)255; return o; };

  // zero-initialized span first (init_kernel covers all of it)
  size_t hist_o  = alloc(HBINS * 4);
  size_t ctrl_o  = alloc(64);
  size_t deg_o   = alloc(N_NODES * 4);
  size_t fill_o  = alloc(N_NODES * 4);
  size_t zero_span = off;  // [0, zero_span) zeroed by init_kernel
  size_t scores_o = alloc(N_NODES * 8);
  size_t cands_o  = alloc(CAND_CAP * 8);
  size_t candi_o  = alloc(CAND_CAP * 4);
  size_t topidx_o = alloc(TOPK * 4);
  size_t gate_o   = alloc(TOPK * 4);
  size_t gi_o     = alloc((size_t)256 * 768 * 4);
  size_t gh_o     = alloc((size_t)256 * 768 * 4);
  size_t wnbt_o   = alloc((size_t)DIM * DIM * 2);     // bf16 transposed W_new
  size_t colval_o = alloc((size_t)N_NODES * SLOT * 8);
  size_t xwb_o    = alloc((size_t)N_NODES * DIM * 2); // bf16 xw
  (void)ws_size; (void)n_in; (void)in_sizes; (void)out_size;

  unsigned* hist  = (unsigned*)(ws + hist_o);
  int*    ctrl    = (int*)(ws + ctrl_o);
  float*  deg     = (float*)(ws + deg_o);
  int*    fill    = (int*)(ws + fill_o);
  double* scores  = (double*)(ws + scores_o);
  double* cand_s  = (double*)(ws + cands_o);
  int*    cand_i  = (int*)(ws + candi_o);
  int*    top_idx = (int*)(ws + topidx_o);
  float*  gate    = (float*)(ws + gate_o);
  float*  gi      = (float*)(ws + gi_o);
  float*  gh      = (float*)(ws + gh_o);
  unsigned short* Wnbt = (unsigned short*)(ws + wnbt_o);
  u64*    colval  = (u64*)(ws + colval_o);
  unsigned short* xwb = (unsigned short*)(ws + xwb_o);

  init_kernel<<<256, 256, 0, stream>>>((unsigned*)ws, (int)(zero_span / 4));
  score_kernel<<<391, 256, 0, stream>>>(X, p, scores, hist);
  findbin_kernel<<<1, 1024, 0, stream>>>(hist, ctrl);
  collect_kernel<<<(N_NODES + 255) / 256, 256, 0, stream>>>(scores, ctrl, cand_s, cand_i);
  sort_kernel<<<1, 1024, 0, stream>>>(ctrl, cand_s, cand_i, p, top_idx, gate);
  gru_gemm_kernel<<<dim3(3, 32, 2), 256, 0, stream>>>(X, top_idx, gate, W0, W_ih, W_hh,
                                                      b_ih, b_hh, gi, gh);
  wnew_kernel<<<256, 256, 0, stream>>>(gi, gh, W0, Wnbt);
  xw_mfma_kernel<<<(N_NODES + 63) / 64, 256, 0, stream>>>(X, Wnbt, xwb);
  scatter_kernel<<<1024, 256, 0, stream>>>(ei, ew, deg, fill, colval);
  agg_kernel<<<2048, 256, 0, stream>>>(xwb, deg, fill, colval, out);
}